// Round 1
// baseline (355.625 us; speedup 1.0000x reference)
//
#include <hip/hip_runtime.h>

// Problem constants: B = 1048576 rows, D = 64 cols.
// xc = [x, sin(x)] (width 128); out[row] = { xc.w_sum + b, exp2(log2|xc| . w_prod) }
// Layout: each thread owns one float4 (4 consecutive elements of a row);
// 16 consecutive lanes own one full row -> perfectly coalesced 16B/lane loads.
// ITER rows-per-thread (grid-strided) amortizes the LDS weight reads.

#define BLOCK 256
#define ITER 4

__global__ __launch_bounds__(BLOCK) void fb_kernel(
    const float4* __restrict__ x4,
    const float*  __restrict__ w_sum,
    const float*  __restrict__ b_sum,
    const float*  __restrict__ w_prod,
    float2*       __restrict__ out)
{
    __shared__ float ws[128];
    __shared__ float wp[128];

    const int tid = threadIdx.x;
    if (tid < 128) {
        ws[tid] = w_sum[tid];
        wp[tid] = w_prod[tid];
    }
    __syncthreads();

    // column group: lane (tid & 15) handles columns [col, col+3]
    const int col = (tid & 15) << 2;
    const float4 wsa = *reinterpret_cast<const float4*>(&ws[col]);       // w_sum for x part
    const float4 wsb = *reinterpret_cast<const float4*>(&ws[64 + col]);  // w_sum for sin part
    const float4 wpa = *reinterpret_cast<const float4*>(&wp[col]);       // w_prod for x part
    const float4 wpb = *reinterpret_cast<const float4*>(&wp[64 + col]);  // w_prod for sin part
    const float  bias = b_sum[0];

    const long stride = (long)gridDim.x * BLOCK;
    const long t0     = (long)blockIdx.x * BLOCK + tid;

#pragma unroll
    for (int it = 0; it < ITER; ++it) {
        const long idx = t0 + (long)it * stride;   // float4 index; row = idx >> 4
        const float4 v = x4[idx];

        float s = 0.f;   // partial dot for sum head
        float p = 0.f;   // partial dot (base-2 log domain) for product head

#define ELEM(X, WSA, WSB, WPA, WPB)                          \
        {                                                    \
            const float xx = (X);                            \
            const float sx = __sinf(xx);                     \
            s = fmaf(xx, (WSA), s);                          \
            s = fmaf(sx, (WSB), s);                          \
            p = fmaf(__log2f(fabsf(xx)), (WPA), p);          \
            p = fmaf(__log2f(fabsf(sx)), (WPB), p);          \
        }

        ELEM(v.x, wsa.x, wsb.x, wpa.x, wpb.x)
        ELEM(v.y, wsa.y, wsb.y, wpa.y, wpb.y)
        ELEM(v.z, wsa.z, wsb.z, wpa.z, wpb.z)
        ELEM(v.w, wsa.w, wsb.w, wpa.w, wpb.w)
#undef ELEM

        // reduce across the 16 lanes that own this row (xor masks stay inside the group)
#pragma unroll
        for (int off = 8; off > 0; off >>= 1) {
            s += __shfl_xor(s, off);
            p += __shfl_xor(p, off);
        }

        if ((tid & 15) == 0) {
            // exp(sum_ln) == exp2(sum_log2); native v_exp_f32 is exp2
            out[idx >> 4] = make_float2(s + bias, __builtin_amdgcn_exp2f(p));
        }
    }
}

extern "C" void kernel_launch(void* const* d_in, const int* in_sizes, int n_in,
                              void* d_out, int out_size, void* d_ws, size_t ws_size,
                              hipStream_t stream)
{
    const float4* x4     = (const float4*)d_in[0];
    const float*  w_sum  = (const float*)d_in[1];
    const float*  b_sum  = (const float*)d_in[2];
    const float*  w_prod = (const float*)d_in[3];
    float2*       out    = (float2*)d_out;

    const long total4 = (long)in_sizes[0] / 4;          // 16,777,216 float4s
    const int  blocks = (int)(total4 / (BLOCK * ITER)); // 16,384 blocks (exact)

    hipLaunchKernelGGL(fb_kernel, dim3(blocks), dim3(BLOCK), 0, stream,
                       x4, w_sum, b_sum, w_prod, out);
}